// Round 5
// baseline (1868.657 us; speedup 1.0000x reference)
//
#include <hip/hip_runtime.h>
#include <math.h>

#define B_RAYS 16384
#define N_I 128
constexpr float RADIUS_ = 1.3f;
constexpr float STEP_ = 0.0203125f;  // 2*1.3/128, exact in fp32

// ---------------- transpose G: [3][16][256][256] -> [3][256][256][16] ----------------
__global__ __launch_bounds__(256) void k_transposeG(const float* __restrict__ G,
                                                    float* __restrict__ Gt) {
    int pl = blockIdx.x >> 8;
    int y  = blockIdx.x & 255;
    __shared__ float tile[16][257];
    int t = threadIdx.x;
#pragma unroll
    for (int ch = 0; ch < 16; ++ch)
        tile[ch][t] = G[((pl * 16 + ch) * 256 + y) * 256 + t];
    __syncthreads();
    float* dst = Gt + (pl * 256 + y) * 256 * 16;
#pragma unroll
    for (int i = 0; i < 16; ++i) {
        int o = i * 256 + t;           // o = x*16 + ch
        dst[o] = tile[o & 15][o >> 4];
    }
}

// ---------------- transpose F: [32][64][64] -> [64][64][32] ----------------
__global__ __launch_bounds__(256) void k_transposeF(const float* __restrict__ F,
                                                    float* __restrict__ Ft) {
    int y = blockIdx.x;  // 0..63
    __shared__ float tile[32][65];
    int t = threadIdx.x;
#pragma unroll
    for (int i = 0; i < 8; ++i) {
        int o = i * 256 + t;  // ch*64 + x
        tile[o >> 6][o & 63] = F[((o >> 6) * 64 + y) * 64 + (o & 63)];
    }
    __syncthreads();
    float* dst = Ft + y * 64 * 32;
#pragma unroll
    for (int i = 0; i < 8; ++i) {
        int o = i * 256 + t;           // o = x*32 + ch
        dst[o] = tile[o & 31][o >> 5];
    }
}

// ---------------- prep: transpose MLP W1s into [j][k] rows (pad cW1 k=31 with 0) ----------------
__global__ __launch_bounds__(256) void k_prepW(const float* __restrict__ sW1,
                                               const float* __restrict__ cW1,
                                               float* __restrict__ w_s1t,
                                               float* __restrict__ w_c1t) {
    int t = threadIdx.x;
    for (int i = t; i < 2048; i += 256) {
        int j = i & 63, k = i >> 6;            // sW1: [32][64], i = k*64 + j
        w_s1t[j * 32 + k] = sW1[i];
    }
    for (int i = t; i < 2048; i += 256) {
        int j = i & 63, k = i >> 6;            // cW1: [31][64]
        w_c1t[j * 32 + k] = (k < 31) ? cW1[k * 64 + j] : 0.f;
    }
}

// ---------------- fused per-sample + composite kernel ----------------
// One wave per ray; lane handles samples 2*lane and 2*lane+1 (static unroll).
// BRANCHLESS sample body: wave-uniform control flow so the compiler can turn
// the (wave-uniform-address) weight reads into s_load -> SGPRs (scalar pipe),
// leaving the vector pipes for the per-lane math. No __shared__ at all.
// waves_per_eu(2,4): allow up to 256 VGPRs, forbid the RA from chasing 8
// waves/EU with spills (round-3 failure: VGPR=64 + 72MB scratch traffic).
__global__ void __launch_bounds__(256)
    __attribute__((amdgpu_waves_per_eu(2, 4))) k_fused(
    const float* __restrict__ rays_o, const float* __restrict__ rays_d,
    const float* __restrict__ Gt, const float* __restrict__ Ft,
    const float* __restrict__ w_s1t, const float* __restrict__ sW2,
    const float* __restrict__ w_c1t, const float* __restrict__ cW2,
    const float* __restrict__ cW3, float* __restrict__ out) {
    int tid  = threadIdx.x;
    int lane = tid & 63;
    int ray  = (blockIdx.x << 2) + (tid >> 6);

    // ---- per-ray setup (hoisted) ----
    float ox = rays_o[ray * 3 + 0], oy = rays_o[ray * 3 + 1], oz = rays_o[ray * 3 + 2];
    float rx = rays_d[ray * 3 + 0], ry = rays_d[ray * 3 + 1], rz = rays_d[ray * 3 + 2];
    float nrm = sqrtf(rx * rx + ry * ry + rz * rz);
    float dx = rx / nrm, dy = ry / nrm, dz = rz / nrm;
    float bq = ox * dx + oy * dy + oz * dz;
    float cq = ox * ox + oy * oy + oz * oz - RADIUS_ * RADIUS_;
    float disc = bq * bq - cq;
    float sq = sqrtf(fmaxf(disc, 0.f));
    float tnear = fmaxf(-bq - sq, 0.f);
    float tfar = -bq + sq;

    // ---- SH deg4 encoding (per-ray, direction-only) ----
    float enc[16];
    {
        float x = dx, y = dy, z = dz;
        float xx = x * x, yy = y * y, zz = z * z;
        float xy = x * y, yz = y * z, xz = x * z;
        enc[0] = 0.28209479177387814f;
        enc[1] = -0.48860251190291987f * y;
        enc[2] = 0.48860251190291987f * z;
        enc[3] = -0.48860251190291987f * x;
        enc[4] = 1.0925484305920792f * xy;
        enc[5] = -1.0925484305920792f * yz;
        enc[6] = 0.94617469575756f * zz - 0.31539156525252f;
        enc[7] = -1.0925484305920792f * xz;
        enc[8] = 0.5462742152960396f * (xx - yy);
        enc[9] = 0.5900435899266435f * y * (-3.0f * xx + yy);
        enc[10] = 2.890611442640554f * xy * z;
        enc[11] = 0.4570457994644657f * y * (1.0f - 5.0f * zz);
        enc[12] = 0.3731763325901154f * z * (5.0f * zz - 3.0f);
        enc[13] = 0.4570457994644657f * x * (1.0f - 5.0f * zz);
        enc[14] = 1.445305721320277f * z * (xx - yy);
        enc[15] = 0.5900435899266435f * x * (-xx + 3.0f * yy);
    }

    // ---- two samples per lane: s = 2*lane + u (branchless bodies) ----
    float4 res[2];
#pragma unroll
    for (int u = 0; u < 2; ++u) {
        int s = (lane << 1) + u;
        float t0 = tnear + (float)s * STEP_;
        float t1 = tnear + (float)(s + 1) * STEP_;
        float tmid = 0.5f * (t0 + t1);
        bool mask = (disc > 0.f) && (tmid <= tfar);

        float px = (ox + dx * tmid) / RADIUS_;
        float py = (oy + dy * tmid) / RADIUS_;
        float pz = (oz + dz * tmid) / RADIUS_;

        // ---- tri-plane bilinear, product over planes (coords clamped -> safe) ----
        float prod[16];
        float cxs[3] = {px, px, py};
        float cys[3] = {py, pz, pz};
#pragma unroll
        for (int pl = 0; pl < 3; ++pl) {
            float fx = fminf(fmaxf((cxs[pl] + 1.0f) * 0.5f * 255.0f, 0.f), 255.f);
            float fy = fminf(fmaxf((cys[pl] + 1.0f) * 0.5f * 255.0f, 0.f), 255.f);
            float x0f = fminf(floorf(fx), 254.f);
            float y0f = fminf(floorf(fy), 254.f);
            int x0 = (int)x0f, y0 = (int)y0f;
            float wx = fx - x0f, wy = fy - y0f;
            float w00 = (1.f - wx) * (1.f - wy), w01 = wx * (1.f - wy);
            float w10 = (1.f - wx) * wy,        w11 = wx * wy;
            const float* b00 = Gt + ((pl * 256 + y0) * 256 + x0) * 16;
#pragma unroll
            for (int q = 0; q < 4; ++q) {
                float4 g00 = *(const float4*)(b00 + q * 4);
                float4 g01 = *(const float4*)(b00 + 16 + q * 4);
                float4 g10 = *(const float4*)(b00 + 4096 + q * 4);
                float4 g11 = *(const float4*)(b00 + 4112 + q * 4);
                float a0 = g00.x * w00 + g01.x * w01 + g10.x * w10 + g11.x * w11;
                float a1 = g00.y * w00 + g01.y * w01 + g10.y * w10 + g11.y * w11;
                float a2 = g00.z * w00 + g01.z * w01 + g10.z * w10 + g11.z * w11;
                float a3 = g00.w * w00 + g01.w * w01 + g10.w * w10 + g11.w * w11;
                if (pl == 0) {
                    prod[q * 4 + 0] = a0; prod[q * 4 + 1] = a1;
                    prod[q * 4 + 2] = a2; prod[q * 4 + 3] = a3;
                } else {
                    prod[q * 4 + 0] *= a0; prod[q * 4 + 1] *= a1;
                    prod[q * 4 + 2] *= a2; prod[q * 4 + 3] *= a3;
                }
            }
        }
        float Gx = prod[0] + prod[1] + prod[2] + prod[3] + prod[4] + prod[5] + prod[6] + prod[7];
        float Gy = prod[8] + prod[9] + prod[10] + prod[11] + prod[12] + prod[13] + prod[14] + prod[15];

        // ---- Fgrid bilinear (32 channels) ----
        float Fv[32];
        {
            float fx = fminf(fmaxf((Gx + 1.0f) * 0.5f * 63.0f, 0.f), 63.f);
            float fy = fminf(fmaxf((Gy + 1.0f) * 0.5f * 63.0f, 0.f), 63.f);
            float x0f = fminf(floorf(fx), 62.f);
            float y0f = fminf(floorf(fy), 62.f);
            int x0 = (int)x0f, y0 = (int)y0f;
            float wx = fx - x0f, wy = fy - y0f;
            float w00 = (1.f - wx) * (1.f - wy), w01 = wx * (1.f - wy);
            float w10 = (1.f - wx) * wy,        w11 = wx * wy;
            const float* f00 = Ft + (y0 * 64 + x0) * 32;
#pragma unroll
            for (int q = 0; q < 8; ++q) {
                float4 g00 = *(const float4*)(f00 + q * 4);
                float4 g01 = *(const float4*)(f00 + 32 + q * 4);
                float4 g10 = *(const float4*)(f00 + 2048 + q * 4);
                float4 g11 = *(const float4*)(f00 + 2048 + 32 + q * 4);
                Fv[q * 4 + 0] = g00.x * w00 + g01.x * w01 + g10.x * w10 + g11.x * w11;
                Fv[q * 4 + 1] = g00.y * w00 + g01.y * w01 + g10.y * w10 + g11.y * w11;
                Fv[q * 4 + 2] = g00.z * w00 + g01.z * w01 + g10.z * w10 + g11.z * w11;
                Fv[q * 4 + 3] = g00.w * w00 + g01.w * w01 + g10.w * w10 + g11.w * w11;
            }
        }

        // ---- sigma MLP fused: hh = relu(Fv@W1) @ W2 (weights scalar-loaded) ----
        float hh[16];
#pragma unroll
        for (int m = 0; m < 16; ++m) hh[m] = 0.f;
        for (int j = 0; j < 64; ++j) {
            const float4* wrow = (const float4*)(w_s1t + j * 32);
            float a0 = 0.f, a1 = 0.f, a2 = 0.f, a3 = 0.f;
#pragma unroll
            for (int q = 0; q < 8; ++q) {
                float4 w = wrow[q];
                a0 = fmaf(Fv[q * 4 + 0], w.x, a0);
                a1 = fmaf(Fv[q * 4 + 1], w.y, a1);
                a2 = fmaf(Fv[q * 4 + 2], w.z, a2);
                a3 = fmaf(Fv[q * 4 + 3], w.w, a3);
            }
            float a = fmaxf((a0 + a1) + (a2 + a3), 0.f);
            const float4* w2row = (const float4*)(sW2 + j * 16);
#pragma unroll
            for (int q = 0; q < 4; ++q) {
                float4 w = w2row[q];
                hh[q * 4 + 0] = fmaf(a, w.x, hh[q * 4 + 0]);
                hh[q * 4 + 1] = fmaf(a, w.y, hh[q * 4 + 1]);
                hh[q * 4 + 2] = fmaf(a, w.z, hh[q * 4 + 2]);
                hh[q * 4 + 3] = fmaf(a, w.w, hh[q * 4 + 3]);
            }
        }

        // ---- color MLP fused: a_j = relu(enc·W1[0:16,j] + feat·W1[16:31,j]) ----
        float c2[64];
#pragma unroll
        for (int m = 0; m < 64; ++m) c2[m] = 0.f;
        for (int j = 0; j < 64; ++j) {
            const float4* wrow = (const float4*)(w_c1t + j * 32);
            float a0 = 0.f, a1 = 0.f, a2 = 0.f, a3 = 0.f;
#pragma unroll
            for (int q = 0; q < 4; ++q) {
                float4 w = wrow[q];
                a0 = fmaf(enc[q * 4 + 0], w.x, a0);
                a1 = fmaf(enc[q * 4 + 1], w.y, a1);
                a2 = fmaf(enc[q * 4 + 2], w.z, a2);
                a3 = fmaf(enc[q * 4 + 3], w.w, a3);
            }
#pragma unroll
            for (int q = 0; q < 4; ++q) {
                float4 w = wrow[4 + q];
                float e0 = hh[q * 4 + 1];
                float e1 = hh[q * 4 + 2];
                float e2 = hh[q * 4 + 3];
                float e3 = (q == 3) ? 0.f : hh[q * 4 + 4];
                a0 = fmaf(e0, w.x, a0);
                a1 = fmaf(e1, w.y, a1);
                a2 = fmaf(e2, w.z, a2);
                a3 = fmaf(e3, w.w, a3);
            }
            float a = fmaxf((a0 + a1) + (a2 + a3), 0.f);
            const float4* w2row = (const float4*)(cW2 + j * 64);
#pragma unroll
            for (int q = 0; q < 16; ++q) {
                float4 w = w2row[q];
                c2[q * 4 + 0] = fmaf(a, w.x, c2[q * 4 + 0]);
                c2[q * 4 + 1] = fmaf(a, w.y, c2[q * 4 + 1]);
                c2[q * 4 + 2] = fmaf(a, w.z, c2[q * 4 + 2]);
                c2[q * 4 + 3] = fmaf(a, w.w, c2[q * 4 + 3]);
            }
        }
        float col0 = 0.f, col1 = 0.f, col2 = 0.f;
#pragma unroll
        for (int m = 0; m < 64; ++m) {
            float v = fmaxf(c2[m], 0.f);
            col0 = fmaf(v, cW3[m * 3 + 0], col0);
            col1 = fmaf(v, cW3[m * 3 + 1], col1);
            col2 = fmaf(v, cW3[m * 3 + 2], col2);
        }

        float sigma = fmaxf(hh[0], 0.f);
        float r = 1.f / (1.f + expf(-col0));
        float g = 1.f / (1.f + expf(-col1));
        float b = 1.f / (1.f + expf(-col2));
        // branchless select (masked-out lanes computed garbage on safe addresses)
        res[u].x = mask ? sigma : 0.f;
        res[u].y = mask ? r : 0.f;
        res[u].z = mask ? g : 0.f;
        res[u].w = mask ? b : 0.f;
    }

    // ---- composite (per-wave scan; identical math to reference cumprod) ----
    int s0 = lane * 2;
    float4 p0 = res[0];
    float4 p1 = res[1];
    float ta = tnear + (float)s0 * STEP_;
    float tb = tnear + (float)(s0 + 1) * STEP_;
    float tc = tnear + (float)(s0 + 2) * STEP_;
    float d0 = tb - ta, d1 = tc - tb;
    float alpha0 = 1.f - expf(-p0.x * d0);
    float alpha1 = 1.f - expf(-p1.x * d1);
    float f0 = (1.f - alpha0) + 1e-10f;
    float f1 = (1.f - alpha1) + 1e-10f;
    float fp = f0 * f1;

    float P = fp;  // inclusive prefix product of lane-pair products
#pragma unroll
    for (int dlt = 1; dlt < 64; dlt <<= 1) {
        float v = __shfl_up(P, dlt, 64);
        if (lane >= dlt) P *= v;
    }
    float E = __shfl_up(P, 1, 64);  // exclusive
    if (lane == 0) E = 1.f;

    float w0 = alpha0 * E;
    float w1 = alpha1 * (E * f0);
    float sr = w0 * p0.y + w1 * p1.y;
    float sg = w0 * p0.z + w1 * p1.z;
    float sb = w0 * p0.w + w1 * p1.w;
    float sa = w0 + w1;
#pragma unroll
    for (int m = 32; m >= 1; m >>= 1) {
        sr += __shfl_xor(sr, m, 64);
        sg += __shfl_xor(sg, m, 64);
        sb += __shfl_xor(sb, m, 64);
        sa += __shfl_xor(sa, m, 64);
    }
    if (lane == 0) {
        float bg = 1.f - sa;
        out[ray * 3 + 0] = sr + bg;
        out[ray * 3 + 1] = sg + bg;
        out[ray * 3 + 2] = sb + bg;
    }
}

extern "C" void kernel_launch(void* const* d_in, const int* in_sizes, int n_in,
                              void* d_out, int out_size, void* d_ws, size_t ws_size,
                              hipStream_t stream) {
    const float* rays_o = (const float*)d_in[0];
    const float* rays_d = (const float*)d_in[1];
    const float* G      = (const float*)d_in[2];
    const float* Fgrid  = (const float*)d_in[3];
    const float* sW1    = (const float*)d_in[4];
    const float* sW2    = (const float*)d_in[5];
    const float* cW1    = (const float*)d_in[6];
    const float* cW2    = (const float*)d_in[7];
    const float* cW3    = (const float*)d_in[8];
    float* out = (float*)d_out;

    char* ws = (char*)d_ws;
    float* Gt    = (float*)ws;                   // 12,582,912 B
    float* Ft    = (float*)(ws + 12582912);      //    524,288 B
    float* w_s1t = (float*)(ws + 13107200);      //      8,192 B
    float* w_c1t = (float*)(ws + 13115392);      //      8,192 B  (total ~13.12 MB)

    k_transposeG<<<768, 256, 0, stream>>>(G, Gt);
    k_transposeF<<<64, 256, 0, stream>>>(Fgrid, Ft);
    k_prepW<<<1, 256, 0, stream>>>(sW1, cW1, w_s1t, w_c1t);
    k_fused<<<B_RAYS / 4, 256, 0, stream>>>(
        rays_o, rays_d, Gt, Ft, w_s1t, sW2, w_c1t, cW2, cW3, out);
}

// Round 6
// 824.295 us; speedup vs baseline: 2.2670x; 2.2670x over previous
//
#include <hip/hip_runtime.h>
#include <math.h>

#define B_RAYS 16384
#define N_I 128
constexpr float RADIUS_ = 1.3f;
constexpr float STEP_ = 0.0203125f;  // 2*1.3/128, exact in fp32

typedef float v2f __attribute__((ext_vector_type(2)));
static __device__ __forceinline__ v2f mk2(float a, float b) { v2f r; r.x = a; r.y = b; return r; }
static __device__ __forceinline__ v2f vfma(v2f a, v2f b, v2f c) {
    return __builtin_elementwise_fma(a, b, c);
}

// ---------------- transpose G: [3][16][256][256] -> [3][256][256][16] ----------------
__global__ __launch_bounds__(256) void k_transposeG(const float* __restrict__ G,
                                                    float* __restrict__ Gt) {
    int pl = blockIdx.x >> 8;
    int y  = blockIdx.x & 255;
    __shared__ float tile[16][257];
    int t = threadIdx.x;
#pragma unroll
    for (int ch = 0; ch < 16; ++ch)
        tile[ch][t] = G[((pl * 16 + ch) * 256 + y) * 256 + t];
    __syncthreads();
    float* dst = Gt + (pl * 256 + y) * 256 * 16;
#pragma unroll
    for (int i = 0; i < 16; ++i) {
        int o = i * 256 + t;           // o = x*16 + ch
        dst[o] = tile[o & 15][o >> 4];
    }
}

// ---------------- transpose F: [32][64][64] -> [64][64][32] ----------------
__global__ __launch_bounds__(256) void k_transposeF(const float* __restrict__ F,
                                                    float* __restrict__ Ft) {
    int y = blockIdx.x;  // 0..63
    __shared__ float tile[32][65];
    int t = threadIdx.x;
#pragma unroll
    for (int i = 0; i < 8; ++i) {
        int o = i * 256 + t;  // ch*64 + x
        tile[o >> 6][o & 63] = F[((o >> 6) * 64 + y) * 64 + (o & 63)];
    }
    __syncthreads();
    float* dst = Ft + y * 64 * 32;
#pragma unroll
    for (int i = 0; i < 8; ++i) {
        int o = i * 256 + t;           // o = x*32 + ch
        dst[o] = tile[o & 31][o >> 5];
    }
}

// ---------------- fused per-sample + composite kernel ----------------
// Round-2 structure (LDS-staged weights, divergent early-out for masked lanes)
// + composite fused in-registers + ALL FMA chains packed onto v2f so the
// backend can select v_pk_fma_f32 (2x fp32 per lane-slot).
__global__ __launch_bounds__(256) void k_fused(
    const float* __restrict__ rays_o, const float* __restrict__ rays_d,
    const float* __restrict__ Gt, const float* __restrict__ Ft,
    const float* __restrict__ sW1, const float* __restrict__ sW2,
    const float* __restrict__ cW1, const float* __restrict__ cW2,
    const float* __restrict__ cW3, float* __restrict__ out) {
    __shared__ float w_s1t[64 * 32];   // [j][k]
    __shared__ float w_s2[64 * 16];    // [j][m]
    __shared__ float w_c1t[64 * 32];   // [j][k], k==31 zeroed
    __shared__ float w_c2[64 * 64];
    __shared__ float w_c3[64 * 3];
    int tid = threadIdx.x;
    for (int i = tid; i < 2048; i += 256) { float v = sW1[i]; w_s1t[(i & 63) * 32 + (i >> 6)] = v; }
    for (int i = tid; i < 1024; i += 256) w_s2[i] = sW2[i];
    for (int i = tid; i < 1984; i += 256) { float v = cW1[i]; w_c1t[(i & 63) * 32 + (i >> 6)] = v; }
    for (int i = tid; i < 64; i += 256) w_c1t[i * 32 + 31] = 0.f;
    for (int i = tid; i < 4096; i += 256) w_c2[i] = cW2[i];
    if (tid < 192) w_c3[tid] = cW3[tid];
    __syncthreads();

    int lane = tid & 63;
    int ray  = (blockIdx.x << 2) + (tid >> 6);

    // ---- per-ray setup ----
    float ox = rays_o[ray * 3 + 0], oy = rays_o[ray * 3 + 1], oz = rays_o[ray * 3 + 2];
    float rx = rays_d[ray * 3 + 0], ry = rays_d[ray * 3 + 1], rz = rays_d[ray * 3 + 2];
    float nrm = sqrtf(rx * rx + ry * ry + rz * rz);
    float dx = rx / nrm, dy = ry / nrm, dz = rz / nrm;
    float bq = ox * dx + oy * dy + oz * dz;
    float cq = ox * ox + oy * oy + oz * oz - RADIUS_ * RADIUS_;
    float disc = bq * bq - cq;
    float sq = sqrtf(fmaxf(disc, 0.f));
    float tnear = fmaxf(-bq - sq, 0.f);
    float tfar = -bq + sq;

    // ---- SH deg4 encoding, packed into pairs e[8] ----
    v2f e[8];
    {
        float x = dx, y = dy, z = dz;
        float xx = x * x, yy = y * y, zz = z * z;
        float xy = x * y, yz = y * z, xz = x * z;
        e[0] = mk2(0.28209479177387814f, -0.48860251190291987f * y);
        e[1] = mk2(0.48860251190291987f * z, -0.48860251190291987f * x);
        e[2] = mk2(1.0925484305920792f * xy, -1.0925484305920792f * yz);
        e[3] = mk2(0.94617469575756f * zz - 0.31539156525252f, -1.0925484305920792f * xz);
        e[4] = mk2(0.5462742152960396f * (xx - yy),
                   0.5900435899266435f * y * (-3.0f * xx + yy));
        e[5] = mk2(2.890611442640554f * xy * z,
                   0.4570457994644657f * y * (1.0f - 5.0f * zz));
        e[6] = mk2(0.3731763325901154f * z * (5.0f * zz - 3.0f),
                   0.4570457994644657f * x * (1.0f - 5.0f * zz));
        e[7] = mk2(1.445305721320277f * z * (xx - yy),
                   0.5900435899266435f * x * (-xx + 3.0f * yy));
    }

    // ---- two samples per lane: s = 2*lane + u ----
    float4 res[2];
#pragma unroll
    for (int u = 0; u < 2; ++u) {
        int s = (lane << 1) + u;
        float t0 = tnear + (float)s * STEP_;
        float t1 = tnear + (float)(s + 1) * STEP_;
        float tmid = 0.5f * (t0 + t1);
        bool mask = (disc > 0.f) && (tmid <= tfar);
        if (!mask) {
            res[u] = make_float4(0.f, 0.f, 0.f, 0.f);
        } else {
            float px = (ox + dx * tmid) / RADIUS_;
            float py = (oy + dy * tmid) / RADIUS_;
            float pz = (oz + dz * tmid) / RADIUS_;

            // ---- tri-plane bilinear (packed), product over planes ----
            v2f pr[8];
            float cxs[3] = {px, px, py};
            float cys[3] = {py, pz, pz};
#pragma unroll
            for (int pl = 0; pl < 3; ++pl) {
                float fx = fminf(fmaxf((cxs[pl] + 1.0f) * 0.5f * 255.0f, 0.f), 255.f);
                float fy = fminf(fmaxf((cys[pl] + 1.0f) * 0.5f * 255.0f, 0.f), 255.f);
                float x0f = fminf(floorf(fx), 254.f);
                float y0f = fminf(floorf(fy), 254.f);
                int x0 = (int)x0f, y0 = (int)y0f;
                float wx = fx - x0f, wy = fy - y0f;
                v2f w00 = mk2((1.f - wx) * (1.f - wy), (1.f - wx) * (1.f - wy));
                v2f w01 = mk2(wx * (1.f - wy), wx * (1.f - wy));
                v2f w10 = mk2((1.f - wx) * wy, (1.f - wx) * wy);
                v2f w11 = mk2(wx * wy, wx * wy);
                const float* b00 = Gt + ((pl * 256 + y0) * 256 + x0) * 16;
#pragma unroll
                for (int q = 0; q < 4; ++q) {
                    float4 g00 = *(const float4*)(b00 + q * 4);
                    float4 g01 = *(const float4*)(b00 + 16 + q * 4);
                    float4 g10 = *(const float4*)(b00 + 4096 + q * 4);
                    float4 g11 = *(const float4*)(b00 + 4112 + q * 4);
                    v2f lo = mk2(g00.x, g00.y) * w00;
                    lo = vfma(mk2(g01.x, g01.y), w01, lo);
                    lo = vfma(mk2(g10.x, g10.y), w10, lo);
                    lo = vfma(mk2(g11.x, g11.y), w11, lo);
                    v2f hi = mk2(g00.z, g00.w) * w00;
                    hi = vfma(mk2(g01.z, g01.w), w01, hi);
                    hi = vfma(mk2(g10.z, g10.w), w10, hi);
                    hi = vfma(mk2(g11.z, g11.w), w11, hi);
                    if (pl == 0) { pr[2 * q] = lo; pr[2 * q + 1] = hi; }
                    else         { pr[2 * q] *= lo; pr[2 * q + 1] *= hi; }
                }
            }
            v2f sx = (pr[0] + pr[1]) + (pr[2] + pr[3]);
            v2f sy = (pr[4] + pr[5]) + (pr[6] + pr[7]);
            float Gx = sx.x + sx.y;
            float Gy = sy.x + sy.y;

            // ---- Fgrid bilinear (32 channels, packed) -> fv[16] pairs ----
            v2f fv[16];
            {
                float fx = fminf(fmaxf((Gx + 1.0f) * 0.5f * 63.0f, 0.f), 63.f);
                float fy = fminf(fmaxf((Gy + 1.0f) * 0.5f * 63.0f, 0.f), 63.f);
                float x0f = fminf(floorf(fx), 62.f);
                float y0f = fminf(floorf(fy), 62.f);
                int x0 = (int)x0f, y0 = (int)y0f;
                float wx = fx - x0f, wy = fy - y0f;
                v2f w00 = mk2((1.f - wx) * (1.f - wy), (1.f - wx) * (1.f - wy));
                v2f w01 = mk2(wx * (1.f - wy), wx * (1.f - wy));
                v2f w10 = mk2((1.f - wx) * wy, (1.f - wx) * wy);
                v2f w11 = mk2(wx * wy, wx * wy);
                const float* f00 = Ft + (y0 * 64 + x0) * 32;
#pragma unroll
                for (int q = 0; q < 8; ++q) {
                    float4 g00 = *(const float4*)(f00 + q * 4);
                    float4 g01 = *(const float4*)(f00 + 32 + q * 4);
                    float4 g10 = *(const float4*)(f00 + 2048 + q * 4);
                    float4 g11 = *(const float4*)(f00 + 2048 + 32 + q * 4);
                    v2f lo = mk2(g00.x, g00.y) * w00;
                    lo = vfma(mk2(g01.x, g01.y), w01, lo);
                    lo = vfma(mk2(g10.x, g10.y), w10, lo);
                    lo = vfma(mk2(g11.x, g11.y), w11, lo);
                    v2f hi = mk2(g00.z, g00.w) * w00;
                    hi = vfma(mk2(g01.z, g01.w), w01, hi);
                    hi = vfma(mk2(g10.z, g10.w), w10, hi);
                    hi = vfma(mk2(g11.z, g11.w), w11, hi);
                    fv[2 * q] = lo;
                    fv[2 * q + 1] = hi;
                }
            }

            // ---- sigma MLP: hh2 = relu(Fv@W1) @ W2, packed accumulators ----
            v2f hh2[8];
#pragma unroll
            for (int m = 0; m < 8; ++m) hh2[m] = mk2(0.f, 0.f);
            for (int j = 0; j < 64; ++j) {
                const float4* wrow = (const float4*)&w_s1t[j * 32];
                v2f aA = mk2(0.f, 0.f), aB = mk2(0.f, 0.f);
#pragma unroll
                for (int q = 0; q < 8; ++q) {
                    float4 w = wrow[q];
                    aA = vfma(fv[2 * q], mk2(w.x, w.y), aA);
                    aB = vfma(fv[2 * q + 1], mk2(w.z, w.w), aB);
                }
                v2f asum = aA + aB;
                float a = fmaxf(asum.x + asum.y, 0.f);
                v2f av = mk2(a, a);
                const float4* w2row = (const float4*)&w_s2[j * 16];
#pragma unroll
                for (int q = 0; q < 4; ++q) {
                    float4 w = w2row[q];
                    hh2[2 * q] = vfma(av, mk2(w.x, w.y), hh2[2 * q]);
                    hh2[2 * q + 1] = vfma(av, mk2(w.z, w.w), hh2[2 * q + 1]);
                }
            }

            // feat pairs for color L1: cf[i] = {hh[2i+1], hh[2i+2]}, cf[7]={hh[15],0}
            v2f cf[8];
            cf[0] = mk2(hh2[0].y, hh2[1].x);
            cf[1] = mk2(hh2[1].y, hh2[2].x);
            cf[2] = mk2(hh2[2].y, hh2[3].x);
            cf[3] = mk2(hh2[3].y, hh2[4].x);
            cf[4] = mk2(hh2[4].y, hh2[5].x);
            cf[5] = mk2(hh2[5].y, hh2[6].x);
            cf[6] = mk2(hh2[6].y, hh2[7].x);
            cf[7] = mk2(hh2[7].y, 0.f);

            // ---- color MLP: a_j = relu([enc|feat]·W1row); c2 += a_j * W2row ----
            v2f c2v[32];
#pragma unroll
            for (int m = 0; m < 32; ++m) c2v[m] = mk2(0.f, 0.f);
            for (int j = 0; j < 64; ++j) {
                const float4* wrow = (const float4*)&w_c1t[j * 32];
                v2f aA = mk2(0.f, 0.f), aB = mk2(0.f, 0.f);
#pragma unroll
                for (int q = 0; q < 4; ++q) {
                    float4 w = wrow[q];
                    aA = vfma(e[2 * q], mk2(w.x, w.y), aA);
                    aB = vfma(e[2 * q + 1], mk2(w.z, w.w), aB);
                }
#pragma unroll
                for (int q = 0; q < 4; ++q) {
                    float4 w = wrow[4 + q];
                    aA = vfma(cf[2 * q], mk2(w.x, w.y), aA);
                    aB = vfma(cf[2 * q + 1], mk2(w.z, w.w), aB);
                }
                v2f asum = aA + aB;
                float a = fmaxf(asum.x + asum.y, 0.f);
                v2f av = mk2(a, a);
                const float4* w2row = (const float4*)&w_c2[j * 64];
#pragma unroll
                for (int q = 0; q < 16; ++q) {
                    float4 w = w2row[q];
                    c2v[2 * q] = vfma(av, mk2(w.x, w.y), c2v[2 * q]);
                    c2v[2 * q + 1] = vfma(av, mk2(w.z, w.w), c2v[2 * q + 1]);
                }
            }
            v2f col01 = mk2(0.f, 0.f);
            float col2 = 0.f;
#pragma unroll
            for (int m = 0; m < 64; ++m) {
                float v = fmaxf((m & 1) ? c2v[m >> 1].y : c2v[m >> 1].x, 0.f);
                col01 = vfma(mk2(v, v), mk2(w_c3[m * 3 + 0], w_c3[m * 3 + 1]), col01);
                col2 = fmaf(v, w_c3[m * 3 + 2], col2);
            }

            float sigma = fmaxf(hh2[0].x, 0.f);
            float r = 1.f / (1.f + expf(-col01.x));
            float g = 1.f / (1.f + expf(-col01.y));
            float b = 1.f / (1.f + expf(-col2));
            res[u] = make_float4(sigma, r, g, b);
        }
    }

    // ---- composite (per-wave scan; identical math to reference cumprod) ----
    int s0 = lane * 2;
    float4 p0 = res[0];
    float4 p1 = res[1];
    float ta = tnear + (float)s0 * STEP_;
    float tb = tnear + (float)(s0 + 1) * STEP_;
    float tc = tnear + (float)(s0 + 2) * STEP_;
    float d0 = tb - ta, d1 = tc - tb;
    float alpha0 = 1.f - expf(-p0.x * d0);
    float alpha1 = 1.f - expf(-p1.x * d1);
    float f0 = (1.f - alpha0) + 1e-10f;
    float f1 = (1.f - alpha1) + 1e-10f;
    float fp = f0 * f1;

    float P = fp;  // inclusive prefix product of lane-pair products
#pragma unroll
    for (int dlt = 1; dlt < 64; dlt <<= 1) {
        float v = __shfl_up(P, dlt, 64);
        if (lane >= dlt) P *= v;
    }
    float E = __shfl_up(P, 1, 64);  // exclusive
    if (lane == 0) E = 1.f;

    float w0 = alpha0 * E;
    float w1 = alpha1 * (E * f0);
    float sr = w0 * p0.y + w1 * p1.y;
    float sg = w0 * p0.z + w1 * p1.z;
    float sb = w0 * p0.w + w1 * p1.w;
    float sa = w0 + w1;
#pragma unroll
    for (int m = 32; m >= 1; m >>= 1) {
        sr += __shfl_xor(sr, m, 64);
        sg += __shfl_xor(sg, m, 64);
        sb += __shfl_xor(sb, m, 64);
        sa += __shfl_xor(sa, m, 64);
    }
    if (lane == 0) {
        float bg = 1.f - sa;
        out[ray * 3 + 0] = sr + bg;
        out[ray * 3 + 1] = sg + bg;
        out[ray * 3 + 2] = sb + bg;
    }
}

extern "C" void kernel_launch(void* const* d_in, const int* in_sizes, int n_in,
                              void* d_out, int out_size, void* d_ws, size_t ws_size,
                              hipStream_t stream) {
    const float* rays_o = (const float*)d_in[0];
    const float* rays_d = (const float*)d_in[1];
    const float* G      = (const float*)d_in[2];
    const float* Fgrid  = (const float*)d_in[3];
    const float* sW1    = (const float*)d_in[4];
    const float* sW2    = (const float*)d_in[5];
    const float* cW1    = (const float*)d_in[6];
    const float* cW2    = (const float*)d_in[7];
    const float* cW3    = (const float*)d_in[8];
    float* out = (float*)d_out;

    char* ws = (char*)d_ws;
    float* Gt = (float*)ws;                  // 12,582,912 B
    float* Ft = (float*)(ws + 12582912);     //    524,288 B  (total 13.1 MB)

    k_transposeG<<<768, 256, 0, stream>>>(G, Gt);
    k_transposeF<<<64, 256, 0, stream>>>(Fgrid, Ft);
    k_fused<<<B_RAYS / 4, 256, 0, stream>>>(
        rays_o, rays_d, Gt, Ft, sW1, sW2, cW1, cW2, cW3, out);
}

// Round 13
// 804.113 us; speedup vs baseline: 2.3239x; 1.0251x over previous
//
#include <hip/hip_runtime.h>
#include <math.h>

#define B_RAYS 16384
#define N_I 128
constexpr float RADIUS_ = 1.3f;
constexpr float STEP_ = 0.0203125f;  // 2*1.3/128, exact in fp32

typedef float v2f __attribute__((ext_vector_type(2)));
static __device__ __forceinline__ v2f mk2(float a, float b) { v2f r; r.x = a; r.y = b; return r; }
static __device__ __forceinline__ v2f vfma(v2f a, v2f b, v2f c) {
    return __builtin_elementwise_fma(a, b, c);
}

// ---------------- transpose G: [3][16][256][256] -> [3][256][256][16] ----------------
__global__ __launch_bounds__(256) void k_transposeG(const float* __restrict__ G,
                                                    float* __restrict__ Gt) {
    int pl = blockIdx.x >> 8;
    int y  = blockIdx.x & 255;
    __shared__ float tile[16][257];
    int t = threadIdx.x;
#pragma unroll
    for (int ch = 0; ch < 16; ++ch)
        tile[ch][t] = G[((pl * 16 + ch) * 256 + y) * 256 + t];
    __syncthreads();
    float* dst = Gt + (pl * 256 + y) * 256 * 16;
#pragma unroll
    for (int i = 0; i < 16; ++i) {
        int o = i * 256 + t;           // o = x*16 + ch
        dst[o] = tile[o & 15][o >> 4];
    }
}

// ---------------- transpose F: [32][64][64] -> [64][64][32] ----------------
__global__ __launch_bounds__(256) void k_transposeF(const float* __restrict__ F,
                                                    float* __restrict__ Ft) {
    int y = blockIdx.x;  // 0..63
    __shared__ float tile[32][65];
    int t = threadIdx.x;
#pragma unroll
    for (int i = 0; i < 8; ++i) {
        int o = i * 256 + t;  // ch*64 + x
        tile[o >> 6][o & 63] = F[((o >> 6) * 64 + y) * 64 + (o & 63)];
    }
    __syncthreads();
    float* dst = Ft + y * 64 * 32;
#pragma unroll
    for (int i = 0; i < 8; ++i) {
        int o = i * 256 + t;           // o = x*32 + ch
        dst[o] = tile[o & 31][o >> 5];
    }
}

// Bilinear gather from a channel-last plane grid; writes 16 v2f (32 channels=Ft)
// or 8 v2f (16 channels=Gt handled inline). Macro to guarantee static indexing.
#define FGRID_GATHER(GXQ, GYQ, FVOUT)                                              \
    {                                                                              \
        float fx = fminf(fmaxf(((GXQ) + 1.0f) * 0.5f * 63.0f, 0.f), 63.f);         \
        float fy = fminf(fmaxf(((GYQ) + 1.0f) * 0.5f * 63.0f, 0.f), 63.f);         \
        float x0f = fminf(floorf(fx), 62.f);                                       \
        float y0f = fminf(floorf(fy), 62.f);                                       \
        int x0 = (int)x0f, y0 = (int)y0f;                                          \
        float wx = fx - x0f, wy = fy - y0f;                                        \
        v2f w00 = mk2((1.f - wx) * (1.f - wy), (1.f - wx) * (1.f - wy));           \
        v2f w01 = mk2(wx * (1.f - wy), wx * (1.f - wy));                           \
        v2f w10 = mk2((1.f - wx) * wy, (1.f - wx) * wy);                           \
        v2f w11 = mk2(wx * wy, wx * wy);                                           \
        const float* f00 = Ft + (y0 * 64 + x0) * 32;                               \
        _Pragma("unroll") for (int q = 0; q < 8; ++q) {                            \
            float4 g00 = *(const float4*)(f00 + q * 4);                            \
            float4 g01 = *(const float4*)(f00 + 32 + q * 4);                       \
            float4 g10 = *(const float4*)(f00 + 2048 + q * 4);                     \
            float4 g11 = *(const float4*)(f00 + 2048 + 32 + q * 4);                \
            v2f lo = mk2(g00.x, g00.y) * w00;                                      \
            lo = vfma(mk2(g01.x, g01.y), w01, lo);                                 \
            lo = vfma(mk2(g10.x, g10.y), w10, lo);                                 \
            lo = vfma(mk2(g11.x, g11.y), w11, lo);                                 \
            v2f hi = mk2(g00.z, g00.w) * w00;                                      \
            hi = vfma(mk2(g01.z, g01.w), w01, hi);                                 \
            hi = vfma(mk2(g10.z, g10.w), w10, hi);                                 \
            hi = vfma(mk2(g11.z, g11.w), w11, hi);                                 \
            FVOUT[2 * q] = lo;                                                     \
            FVOUT[2 * q + 1] = hi;                                                 \
        }                                                                          \
    }

// Tri-plane gather+product for one sample -> Gx,Gy. Static indexing via unroll.
#define TRIPLANE(PX, PY, PZ, GXOUT, GYOUT)                                         \
    {                                                                              \
        v2f pr[8];                                                                 \
        float cxs[3] = {(PX), (PX), (PY)};                                         \
        float cys[3] = {(PY), (PZ), (PZ)};                                         \
        _Pragma("unroll") for (int pl = 0; pl < 3; ++pl) {                         \
            float fx = fminf(fmaxf((cxs[pl] + 1.0f) * 0.5f * 255.0f, 0.f), 255.f); \
            float fy = fminf(fmaxf((cys[pl] + 1.0f) * 0.5f * 255.0f, 0.f), 255.f); \
            float x0f = fminf(floorf(fx), 254.f);                                  \
            float y0f = fminf(floorf(fy), 254.f);                                  \
            int x0 = (int)x0f, y0 = (int)y0f;                                      \
            float wx = fx - x0f, wy = fy - y0f;                                    \
            v2f w00 = mk2((1.f - wx) * (1.f - wy), (1.f - wx) * (1.f - wy));       \
            v2f w01 = mk2(wx * (1.f - wy), wx * (1.f - wy));                       \
            v2f w10 = mk2((1.f - wx) * wy, (1.f - wx) * wy);                       \
            v2f w11 = mk2(wx * wy, wx * wy);                                       \
            const float* b00 = Gt + ((pl * 256 + y0) * 256 + x0) * 16;             \
            _Pragma("unroll") for (int q = 0; q < 4; ++q) {                        \
                float4 g00 = *(const float4*)(b00 + q * 4);                        \
                float4 g01 = *(const float4*)(b00 + 16 + q * 4);                   \
                float4 g10 = *(const float4*)(b00 + 4096 + q * 4);                 \
                float4 g11 = *(const float4*)(b00 + 4112 + q * 4);                 \
                v2f lo = mk2(g00.x, g00.y) * w00;                                  \
                lo = vfma(mk2(g01.x, g01.y), w01, lo);                             \
                lo = vfma(mk2(g10.x, g10.y), w10, lo);                             \
                lo = vfma(mk2(g11.x, g11.y), w11, lo);                             \
                v2f hi = mk2(g00.z, g00.w) * w00;                                  \
                hi = vfma(mk2(g01.z, g01.w), w01, hi);                             \
                hi = vfma(mk2(g10.z, g10.w), w10, hi);                             \
                hi = vfma(mk2(g11.z, g11.w), w11, hi);                             \
                if (pl == 0) { pr[2 * q] = lo; pr[2 * q + 1] = hi; }               \
                else         { pr[2 * q] *= lo; pr[2 * q + 1] *= hi; }             \
            }                                                                      \
        }                                                                          \
        v2f sx = (pr[0] + pr[1]) + (pr[2] + pr[3]);                                \
        v2f sy = (pr[4] + pr[5]) + (pr[6] + pr[7]);                                \
        GXOUT = sx.x + sx.y;                                                       \
        GYOUT = sy.x + sy.y;                                                       \
    }

// ---------------- fused per-sample + composite kernel ----------------
// One wave per ray; lane handles samples 2*lane (A) and 2*lane+1 (B).
// BOTH samples share every LDS weight-row read (u-fusion): the j-loops read
// each row once and feed two samples' accumulators, halving LDS instructions
// (round-6 diagnosis: LDS-pipe issue-bound, not VALU-bound).
// maskB implies maskA (tmidB > tmidA, same disc), so one divergent region.
__global__ void __launch_bounds__(256)
    __attribute__((amdgpu_waves_per_eu(2, 4))) k_fused(
    const float* __restrict__ rays_o, const float* __restrict__ rays_d,
    const float* __restrict__ Gt, const float* __restrict__ Ft,
    const float* __restrict__ sW1, const float* __restrict__ sW2,
    const float* __restrict__ cW1, const float* __restrict__ cW2,
    const float* __restrict__ cW3, float* __restrict__ out) {
    __shared__ float w_s1t[64 * 32];   // [j][k]
    __shared__ float w_s2[64 * 16];    // [j][m]
    __shared__ float w_c1t[64 * 32];   // [j][k], k==31 zeroed
    __shared__ float w_c2[64 * 64];    // [j][m]
    __shared__ float w_c3t[3 * 64];    // transposed: [c][m] for b128 reads
    int tid = threadIdx.x;
    for (int i = tid; i < 2048; i += 256) { float v = sW1[i]; w_s1t[(i & 63) * 32 + (i >> 6)] = v; }
    for (int i = tid; i < 1024; i += 256) w_s2[i] = sW2[i];
    for (int i = tid; i < 1984; i += 256) { float v = cW1[i]; w_c1t[(i & 63) * 32 + (i >> 6)] = v; }
    for (int i = tid; i < 64; i += 256) w_c1t[i * 32 + 31] = 0.f;
    for (int i = tid; i < 4096; i += 256) w_c2[i] = cW2[i];
    if (tid < 192) w_c3t[(tid % 3) * 64 + tid / 3] = cW3[tid];
    __syncthreads();

    int lane = tid & 63;
    int ray  = (blockIdx.x << 2) + (tid >> 6);

    // ---- per-ray setup ----
    float ox = rays_o[ray * 3 + 0], oy = rays_o[ray * 3 + 1], oz = rays_o[ray * 3 + 2];
    float rx = rays_d[ray * 3 + 0], ry = rays_d[ray * 3 + 1], rz = rays_d[ray * 3 + 2];
    float nrm = sqrtf(rx * rx + ry * ry + rz * rz);
    float dx = rx / nrm, dy = ry / nrm, dz = rz / nrm;
    float bq = ox * dx + oy * dy + oz * dz;
    float cq = ox * ox + oy * oy + oz * oz - RADIUS_ * RADIUS_;
    float disc = bq * bq - cq;
    float sq = sqrtf(fmaxf(disc, 0.f));
    float tnear = fmaxf(-bq - sq, 0.f);
    float tfar = -bq + sq;

    // ---- SH deg4 encoding, packed pairs (shared by both samples) ----
    v2f e[8];
    {
        float x = dx, y = dy, z = dz;
        float xx = x * x, yy = y * y, zz = z * z;
        float xy = x * y, yz = y * z, xz = x * z;
        e[0] = mk2(0.28209479177387814f, -0.48860251190291987f * y);
        e[1] = mk2(0.48860251190291987f * z, -0.48860251190291987f * x);
        e[2] = mk2(1.0925484305920792f * xy, -1.0925484305920792f * yz);
        e[3] = mk2(0.94617469575756f * zz - 0.31539156525252f, -1.0925484305920792f * xz);
        e[4] = mk2(0.5462742152960396f * (xx - yy),
                   0.5900435899266435f * y * (-3.0f * xx + yy));
        e[5] = mk2(2.890611442640554f * xy * z,
                   0.4570457994644657f * y * (1.0f - 5.0f * zz));
        e[6] = mk2(0.3731763325901154f * z * (5.0f * zz - 3.0f),
                   0.4570457994644657f * x * (1.0f - 5.0f * zz));
        e[7] = mk2(1.445305721320277f * z * (xx - yy),
                   0.5900435899266435f * x * (-xx + 3.0f * yy));
    }

    // ---- sample times/masks (A = 2*lane, B = 2*lane+1) ----
    int sA = lane << 1;
    float t0A = tnear + (float)sA * STEP_;
    float t1A = tnear + (float)(sA + 1) * STEP_;
    float t1B = tnear + (float)(sA + 2) * STEP_;
    float tmidA = 0.5f * (t0A + t1A);
    float tmidB = 0.5f * (t1A + t1B);
    bool maskA = (disc > 0.f) && (tmidA <= tfar);
    bool maskB = (disc > 0.f) && (tmidB <= tfar);   // maskB => maskA

    float4 resA = make_float4(0.f, 0.f, 0.f, 0.f);
    float4 resB = make_float4(0.f, 0.f, 0.f, 0.f);

    if (maskA) {
        float pxA = (ox + dx * tmidA) / RADIUS_;
        float pyA = (oy + dy * tmidA) / RADIUS_;
        float pzA = (oz + dz * tmidA) / RADIUS_;
        float pxB = (ox + dx * tmidB) / RADIUS_;
        float pyB = (oy + dy * tmidB) / RADIUS_;
        float pzB = (oz + dz * tmidB) / RADIUS_;

        float GxA, GyA, GxB, GyB;
        TRIPLANE(pxA, pyA, pzA, GxA, GyA);
        TRIPLANE(pxB, pyB, pzB, GxB, GyB);

        v2f fvA[16], fvB[16];
        FGRID_GATHER(GxA, GyA, fvA);
        FGRID_GATHER(GxB, GyB, fvB);

        // ---- sigma MLP, u-fused: one weight-row read feeds both samples ----
        v2f hhA[8], hhB[8];
#pragma unroll
        for (int m = 0; m < 8; ++m) { hhA[m] = mk2(0.f, 0.f); hhB[m] = mk2(0.f, 0.f); }
        for (int j = 0; j < 64; ++j) {
            const float4* wrow = (const float4*)&w_s1t[j * 32];
            v2f aA0 = mk2(0.f, 0.f), aB0 = mk2(0.f, 0.f);
            v2f aA1 = mk2(0.f, 0.f), aB1 = mk2(0.f, 0.f);
#pragma unroll
            for (int q = 0; q < 8; ++q) {
                float4 w = wrow[q];
                v2f wlo = mk2(w.x, w.y), whi = mk2(w.z, w.w);
                aA0 = vfma(fvA[2 * q], wlo, aA0);
                aB0 = vfma(fvA[2 * q + 1], whi, aB0);
                aA1 = vfma(fvB[2 * q], wlo, aA1);
                aB1 = vfma(fvB[2 * q + 1], whi, aB1);
            }
            v2f s0 = aA0 + aB0;
            v2f s1 = aA1 + aB1;
            float a0 = fmaxf(s0.x + s0.y, 0.f);
            float a1 = fmaxf(s1.x + s1.y, 0.f);
            v2f av0 = mk2(a0, a0), av1 = mk2(a1, a1);
            const float4* w2row = (const float4*)&w_s2[j * 16];
#pragma unroll
            for (int q = 0; q < 4; ++q) {
                float4 w = w2row[q];
                v2f wlo = mk2(w.x, w.y), whi = mk2(w.z, w.w);
                hhA[2 * q] = vfma(av0, wlo, hhA[2 * q]);
                hhA[2 * q + 1] = vfma(av0, whi, hhA[2 * q + 1]);
                hhB[2 * q] = vfma(av1, wlo, hhB[2 * q]);
                hhB[2 * q + 1] = vfma(av1, whi, hhB[2 * q + 1]);
            }
        }

        float sigmaA = fmaxf(hhA[0].x, 0.f);
        float sigmaB = fmaxf(hhB[0].x, 0.f);

        // feat pairs: cf[i] = {hh[2i+1], hh[2i+2]}, cf[7] = {hh[15], 0}
        v2f cfA[8], cfB[8];
        cfA[0] = mk2(hhA[0].y, hhA[1].x); cfB[0] = mk2(hhB[0].y, hhB[1].x);
        cfA[1] = mk2(hhA[1].y, hhA[2].x); cfB[1] = mk2(hhB[1].y, hhB[2].x);
        cfA[2] = mk2(hhA[2].y, hhA[3].x); cfB[2] = mk2(hhB[2].y, hhB[3].x);
        cfA[3] = mk2(hhA[3].y, hhA[4].x); cfB[3] = mk2(hhB[3].y, hhB[4].x);
        cfA[4] = mk2(hhA[4].y, hhA[5].x); cfB[4] = mk2(hhB[4].y, hhB[5].x);
        cfA[5] = mk2(hhA[5].y, hhA[6].x); cfB[5] = mk2(hhB[5].y, hhB[6].x);
        cfA[6] = mk2(hhA[6].y, hhA[7].x); cfB[6] = mk2(hhB[6].y, hhB[7].x);
        cfA[7] = mk2(hhA[7].y, 0.f);      cfB[7] = mk2(hhB[7].y, 0.f);

        // ---- color MLP, u-fused ----
        v2f c2A[32], c2B[32];
#pragma unroll
        for (int m = 0; m < 32; ++m) { c2A[m] = mk2(0.f, 0.f); c2B[m] = mk2(0.f, 0.f); }
        for (int j = 0; j < 64; ++j) {
            const float4* wrow = (const float4*)&w_c1t[j * 32];
            v2f aA0 = mk2(0.f, 0.f), aB0 = mk2(0.f, 0.f);
            v2f aA1 = mk2(0.f, 0.f), aB1 = mk2(0.f, 0.f);
#pragma unroll
            for (int q = 0; q < 4; ++q) {
                float4 w = wrow[q];
                v2f wlo = mk2(w.x, w.y), whi = mk2(w.z, w.w);
                aA0 = vfma(e[2 * q], wlo, aA0);          // enc shared
                aB0 = vfma(e[2 * q + 1], whi, aB0);
                aA1 = vfma(e[2 * q], wlo, aA1);
                aB1 = vfma(e[2 * q + 1], whi, aB1);
            }
#pragma unroll
            for (int q = 0; q < 4; ++q) {
                float4 w = wrow[4 + q];
                v2f wlo = mk2(w.x, w.y), whi = mk2(w.z, w.w);
                aA0 = vfma(cfA[2 * q], wlo, aA0);
                aB0 = vfma(cfA[2 * q + 1], whi, aB0);
                aA1 = vfma(cfB[2 * q], wlo, aA1);
                aB1 = vfma(cfB[2 * q + 1], whi, aB1);
            }
            v2f s0 = aA0 + aB0;
            v2f s1 = aA1 + aB1;
            float a0 = fmaxf(s0.x + s0.y, 0.f);
            float a1 = fmaxf(s1.x + s1.y, 0.f);
            v2f av0 = mk2(a0, a0), av1 = mk2(a1, a1);
            const float4* w2row = (const float4*)&w_c2[j * 64];
#pragma unroll
            for (int q = 0; q < 16; ++q) {
                float4 w = w2row[q];
                v2f wlo = mk2(w.x, w.y), whi = mk2(w.z, w.w);
                c2A[2 * q] = vfma(av0, wlo, c2A[2 * q]);
                c2A[2 * q + 1] = vfma(av0, whi, c2A[2 * q + 1]);
                c2B[2 * q] = vfma(av1, wlo, c2B[2 * q]);
                c2B[2 * q + 1] = vfma(av1, whi, c2B[2 * q + 1]);
            }
        }

        // ---- final color layer, transposed-b128 weight reads, both samples ----
        v2f colA01 = mk2(0.f, 0.f), colB01 = mk2(0.f, 0.f);
        float colA2 = 0.f, colB2 = 0.f;
#pragma unroll
        for (int mq = 0; mq < 16; ++mq) {
            float4 wr = *(const float4*)&w_c3t[mq * 4];
            float4 wg = *(const float4*)&w_c3t[64 + mq * 4];
            float4 wb = *(const float4*)&w_c3t[128 + mq * 4];
            v2f vaA = c2A[2 * mq], vbA = c2A[2 * mq + 1];
            v2f vaB = c2B[2 * mq], vbB = c2B[2 * mq + 1];
            float vA0 = fmaxf(vaA.x, 0.f), vA1 = fmaxf(vaA.y, 0.f);
            float vA2 = fmaxf(vbA.x, 0.f), vA3 = fmaxf(vbA.y, 0.f);
            float vB0 = fmaxf(vaB.x, 0.f), vB1 = fmaxf(vaB.y, 0.f);
            float vB2 = fmaxf(vbB.x, 0.f), vB3 = fmaxf(vbB.y, 0.f);
            colA01 = vfma(mk2(vA0, vA0), mk2(wr.x, wg.x), colA01);
            colA01 = vfma(mk2(vA1, vA1), mk2(wr.y, wg.y), colA01);
            colA01 = vfma(mk2(vA2, vA2), mk2(wr.z, wg.z), colA01);
            colA01 = vfma(mk2(vA3, vA3), mk2(wr.w, wg.w), colA01);
            colA2 = fmaf(vA0, wb.x, colA2);
            colA2 = fmaf(vA1, wb.y, colA2);
            colA2 = fmaf(vA2, wb.z, colA2);
            colA2 = fmaf(vA3, wb.w, colA2);
            colB01 = vfma(mk2(vB0, vB0), mk2(wr.x, wg.x), colB01);
            colB01 = vfma(mk2(vB1, vB1), mk2(wr.y, wg.y), colB01);
            colB01 = vfma(mk2(vB2, vB2), mk2(wr.z, wg.z), colB01);
            colB01 = vfma(mk2(vB3, vB3), mk2(wr.w, wg.w), colB01);
            colB2 = fmaf(vB0, wb.x, colB2);
            colB2 = fmaf(vB1, wb.y, colB2);
            colB2 = fmaf(vB2, wb.z, colB2);
            colB2 = fmaf(vB3, wb.w, colB2);
        }

        resA = make_float4(sigmaA,
                           1.f / (1.f + expf(-colA01.x)),
                           1.f / (1.f + expf(-colA01.y)),
                           1.f / (1.f + expf(-colA2)));
        if (maskB) {
            resB = make_float4(sigmaB,
                               1.f / (1.f + expf(-colB01.x)),
                               1.f / (1.f + expf(-colB01.y)),
                               1.f / (1.f + expf(-colB2)));
        }
    }

    // ---- composite (per-wave scan; identical math to reference cumprod) ----
    int s0i = lane * 2;
    float ta = tnear + (float)s0i * STEP_;
    float tb = tnear + (float)(s0i + 1) * STEP_;
    float tc = tnear + (float)(s0i + 2) * STEP_;
    float d0 = tb - ta, d1 = tc - tb;
    float alpha0 = 1.f - expf(-resA.x * d0);
    float alpha1 = 1.f - expf(-resB.x * d1);
    float f0 = (1.f - alpha0) + 1e-10f;
    float f1 = (1.f - alpha1) + 1e-10f;
    float fp = f0 * f1;

    float P = fp;  // inclusive prefix product of lane-pair products
#pragma unroll
    for (int dlt = 1; dlt < 64; dlt <<= 1) {
        float v = __shfl_up(P, dlt, 64);
        if (lane >= dlt) P *= v;
    }
    float E = __shfl_up(P, 1, 64);  // exclusive
    if (lane == 0) E = 1.f;

    float w0 = alpha0 * E;
    float w1 = alpha1 * (E * f0);
    float sr = w0 * resA.y + w1 * resB.y;
    float sg = w0 * resA.z + w1 * resB.z;
    float sb = w0 * resA.w + w1 * resB.w;
    float sa = w0 + w1;
#pragma unroll
    for (int m = 32; m >= 1; m >>= 1) {
        sr += __shfl_xor(sr, m, 64);
        sg += __shfl_xor(sg, m, 64);
        sb += __shfl_xor(sb, m, 64);
        sa += __shfl_xor(sa, m, 64);
    }
    if (lane == 0) {
        float bg = 1.f - sa;
        out[ray * 3 + 0] = sr + bg;
        out[ray * 3 + 1] = sg + bg;
        out[ray * 3 + 2] = sb + bg;
    }
}

extern "C" void kernel_launch(void* const* d_in, const int* in_sizes, int n_in,
                              void* d_out, int out_size, void* d_ws, size_t ws_size,
                              hipStream_t stream) {
    const float* rays_o = (const float*)d_in[0];
    const float* rays_d = (const float*)d_in[1];
    const float* G      = (const float*)d_in[2];
    const float* Fgrid  = (const float*)d_in[3];
    const float* sW1    = (const float*)d_in[4];
    const float* sW2    = (const float*)d_in[5];
    const float* cW1    = (const float*)d_in[6];
    const float* cW2    = (const float*)d_in[7];
    const float* cW3    = (const float*)d_in[8];
    float* out = (float*)d_out;

    char* ws = (char*)d_ws;
    float* Gt = (float*)ws;                  // 12,582,912 B
    float* Ft = (float*)(ws + 12582912);     //    524,288 B  (total 13.1 MB)

    k_transposeG<<<768, 256, 0, stream>>>(G, Gt);
    k_transposeF<<<64, 256, 0, stream>>>(Fgrid, Ft);
    k_fused<<<B_RAYS / 4, 256, 0, stream>>>(
        rays_o, rays_d, Gt, Ft, sW1, sW2, cW1, cW2, cW3, out);
}